// Round 10
// baseline (225.420 us; speedup 1.0000x reference)
//
#include <hip/hip_runtime.h>
#include <math.h>

#define EPSF 1e-6f

typedef float v4f __attribute__((ext_vector_type(4)));
typedef int   v2i __attribute__((ext_vector_type(2)));

struct F3   { float x, y, z; };
struct Quat { float x, y, z, w; };
struct Sim3 { F3 t; Quat q; float s; };

__device__ __forceinline__ F3 cross3(F3 a, F3 b) {
    return { a.y*b.z - a.z*b.y, a.z*b.x - a.x*b.z, a.x*b.y - a.y*b.x };
}

__device__ __forceinline__ F3 quat_rotate(Quat q, F3 v) {
    F3 qv { q.x, q.y, q.z };
    F3 uv  = cross3(qv, v);
    F3 cuv = cross3(qv, uv);
    return { v.x + 2.0f*(q.w*uv.x + cuv.x),
             v.y + 2.0f*(q.w*uv.y + cuv.y),
             v.z + 2.0f*(q.w*uv.z + cuv.z) };
}

__device__ __forceinline__ Quat quat_mul(Quat a, Quat b) {
    return {
        a.w*b.x + a.x*b.w + a.y*b.z - a.z*b.y,
        a.w*b.y - a.x*b.z + a.y*b.w + a.z*b.x,
        a.w*b.z + a.x*b.y - a.y*b.x + a.z*b.w,
        a.w*b.w - a.x*b.x - a.y*b.y - a.z*b.z
    };
}

__device__ __forceinline__ Sim3 sim3_inv(Sim3 T) {
    Quat qi { -T.q.x, -T.q.y, -T.q.z, T.q.w };
    float si = __fdividef(1.0f, T.s);
    F3 r = quat_rotate(qi, T.t);
    return { { -si*r.x, -si*r.y, -si*r.z }, qi, si };
}

__device__ __forceinline__ Sim3 sim3_mul(Sim3 A, Sim3 B) {
    F3 r = quat_rotate(A.q, B.t);
    return { { A.t.x + A.s*r.x, A.t.y + A.s*r.y, A.t.z + A.s*r.z },
             quat_mul(A.q, B.q), A.s * B.s };
}

// direct global load (rows 32 B, 16-B aligned)
__device__ __forceinline__ Sim3 load_sim3(const float* __restrict__ p) {
    v4f a = *reinterpret_cast<const v4f*>(p);
    v4f b = *reinterpret_cast<const v4f*>(p + 4);
    return { {a.x, a.y, a.z}, {a.w, b.x, b.y, b.z}, b.w };
}

// LDS Sim3 read, half-split layout: first 16 B at p, second 16 B at p+256 floats
__device__ __forceinline__ Sim3 lds_sim3_split(const float* p) {
    v4f a = *reinterpret_cast<const v4f*>(p);
    v4f b = *reinterpret_cast<const v4f*>(p + 256);
    return { {a.x, a.y, a.z}, {a.w, b.x, b.y, b.z}, b.w };
}

// atan2 for y >= 0 -> [0, pi].  A&S 4.4.49 polynomial, |err| <= 1e-5 rad.
__device__ __forceinline__ float fast_atan2_pos(float y, float x) {
    float ax = fabsf(x);
    float mn = fminf(y, ax);
    float mx = fmaxf(y, ax);
    float t  = __fdividef(mn, mx);
    float s  = t * t;
    float p  = fmaf(s, 0.0208351f, -0.0851330f);
    p = fmaf(s, p,  0.1801410f);
    p = fmaf(s, p, -0.3302995f);
    p = fmaf(s, p,  0.9998660f);
    float r = t * p;
    r = (y > ax)   ? (1.5707963268f - r) : r;
    r = (x < 0.0f) ? (3.1415926536f - r) : r;
    return r;
}

// sim3_log: mirrors the jax reference; generic A,B,C under wave-uniform
// branch; f32 Cramer (absmax 0.5 vs 4.88 threshold, verified r4-r8).
__device__ __forceinline__ void sim3_log(Sim3 T, float out[7]) {
    float qx = T.q.x, qy = T.q.y, qz = T.q.z, qw = T.q.w;
    float nv = sqrtf(qx*qx + qy*qy + qz*qz);
    float theta_r = 2.0f * fast_atan2_pos(nv, qw);
    bool  nv_small = nv < EPSF;
    float fac = nv_small ? 2.0f : __fdividef(theta_r, nv);
    float px = fac*qx, py = fac*qy, pz = fac*qz;
    float sigma = __logf(T.s);
    float theta = nv_small ? 2.0f*nv : theta_r;

    bool sig_small = fabsf(sigma) < EPSF;
    bool th_small  = theta < EPSF;
    float scale = __expf(sigma);
    float A, B, C;
    if (!sig_small && !th_small) {
        float th = theta, sg = sigma;
        float th2 = th*th, sg2 = sg*sg;
        C = __fdividef(scale - 1.0f, sg);
        float sth = __sinf(th), cth = __cosf(th);
        float a = scale * sth;
        float b = scale * cth;
        float c = th2 + sg2;
        float rc = __fdividef(1.0f, c);
        A = __fdividef(fmaf(a, sg, (1.0f - b)*th), th * c);
        B = __fdividef(C - fmaf(b - 1.0f, sg, a*th) * rc, th2);
    } else {
        float sg = sig_small ? 1.0f : sigma;
        float th = th_small  ? 1.0f : theta;
        float th2 = th*th, sg2 = sg*sg;
        C = sig_small ? 1.0f : __fdividef(scale - 1.0f, sg);
        float sth = __sinf(th), cth = __cosf(th);
        float A_ss = th_small ? 0.5f : __fdividef(1.0f - cth, th2);
        float B_ss = th_small ? (1.0f/6.0f) : __fdividef(th - sth, th2 * th);
        float a = scale * sth;
        float b = scale * cth;
        float c = th2 + sg2;
        float rc = __fdividef(1.0f, c);
        float A_g = __fdividef(fmaf(a, sg, (1.0f - b)*th), th * c);
        float B_g = __fdividef(C - fmaf(b - 1.0f, sg, a*th) * rc, th2);
        float A_ts = __fdividef(fmaf(sg - 1.0f, scale, 1.0f), sg2);
        float B_ts = __fdividef(fmaf(scale, fmaf(sg, sg - 2.0f, 2.0f), -2.0f), 2.0f*sg2*sg);
        A = sig_small ? A_ss : (th_small ? A_ts : A_g);
        B = sig_small ? B_ss : (th_small ? B_ts : B_g);
    }

    float P01 = -pz, P02 =  py;
    float P10 =  pz, P12 = -px;
    float P20 = -py, P21 =  px;
    float Q00 = P01*P10 + P02*P20;
    float Q01 = P02*P21;
    float Q02 = P01*P12;
    float Q10 = P12*P20;
    float Q11 = P10*P01 + P12*P21;
    float Q12 = P10*P02;
    float Q20 = P21*P10;
    float Q21 = P20*P01;
    float Q22 = P20*P02 + P21*P12;

    float W00 = C + B*Q00,          W01 = A*P01 + B*Q01, W02 = A*P02 + B*Q02;
    float W10 = A*P10 + B*Q10,      W11 = C + B*Q11,     W12 = A*P12 + B*Q12;
    float W20 = A*P20 + B*Q20,      W21 = A*P21 + B*Q21, W22 = C + B*Q22;

    float c00 = fmaf(W11, W22, -W12*W21);
    float c01 = fmaf(W12, W20, -W10*W22);
    float c02 = fmaf(W10, W21, -W11*W20);
    float a01 = fmaf(W02, W21, -W01*W22);
    float a02 = fmaf(W01, W12, -W02*W11);
    float a11 = fmaf(W00, W22, -W02*W20);
    float a12 = fmaf(W02, W10, -W00*W12);
    float a21 = fmaf(W01, W20, -W00*W21);
    float a22 = fmaf(W00, W11, -W01*W10);
    float det = fmaf(W00, c00, fmaf(W01, c01, W02*c02));
    float idet = __fdividef(1.0f, det);
    float tx = T.t.x, ty = T.t.y, tz = T.t.z;
    out[0] = fmaf(c00, tx, fmaf(a01, ty, a02*tz)) * idet;
    out[1] = fmaf(c01, tx, fmaf(a11, ty, a12*tz)) * idet;
    out[2] = fmaf(c02, tx, fmaf(a21, ty, a22*tz)) * idet;
    out[3] = px; out[4] = py; out[5] = pz; out[6] = sigma;
}

// ---- LDS staging, 16-B global_load_lds ONLY (gld12 removed: 12-B variant
// was never HW-verified; r9's finite-absmax forensics point at its LDS
// lane-stride overrunning the weight regions).  Per-tile layout (floats):
//   TP[0,512) TO[512,1024) TL[1024,1536) PW[1536,2048) OW[2048,2560)
// Sim3 streams half-split (first 16B at base+lane*4, second at +256).
// Weight arrays staged as 512 linear floats (over-reads into next tile's
// weights -- in-bounds for all tiles except the last, which takes the
// direct-load path).
#define TPo 0
#define TOo 512
#define TLo 1024
#define PWo 1536
#define OWo 2048
#define BUF_FLOATS 2560

__device__ __forceinline__ void gld16(const float* g, float* l) {
    __builtin_amdgcn_global_load_lds(
        (const __attribute__((address_space(1))) void*)g,
        (__attribute__((address_space(3))) void*)l, 16, 0, 0);
}

// stage one 64-item tile (10 x 16-B async instructions, 10.2 KB)
__device__ __forceinline__ void stage_tile(
        float* buf, unsigned tile,
        const float* __restrict__ Tp_inv, const float* __restrict__ To_inv,
        const float* __restrict__ T_lc,  const float* __restrict__ pw,
        const float* __restrict__ ow, unsigned n, unsigned lane) {
    // all clamps rounded down to 16-B alignment
    unsigned smax = (n*8u - 4u) & ~3u;
    unsigned b0 = tile*512u + lane*8u;
    unsigned b1 = b0 + 4u;
    b0 = b0 < smax ? b0 : smax;
    b1 = b1 < smax ? b1 : smax;
    gld16(Tp_inv + b0, buf + TPo);
    gld16(Tp_inv + b1, buf + TPo + 256);
    gld16(To_inv + b0, buf + TOo);
    gld16(To_inv + b1, buf + TOo + 256);
    gld16(T_lc  + b0, buf + TLo);
    gld16(T_lc  + b1, buf + TLo + 256);
    unsigned wmax = (n*7u - 4u) & ~3u;
    unsigned w0 = tile*448u + lane*4u;
    unsigned w1 = w0 + 256u;
    w0 = w0 < wmax ? w0 : wmax;
    w1 = w1 < wmax ? w1 : wmax;
    gld16(pw + w0, buf + PWo);
    gld16(pw + w1, buf + PWo + 256);
    gld16(ow + w0, buf + OWo);
    gld16(ow + w1, buf + OWo + 256);
}

// Persistent 1-wave blocks, double-buffered global_load_lds pipeline:
//   stage(t+1) || compute(t); one vmcnt(0) per iteration.
// Rationale (r8): VGPR=52 proved the compiler sinks register loads to
// their uses -> ~3.3 TB/s concurrency cap.  global_load_lds is VGPR-free
// and side-effecting -> cannot be sunk; tile t+1's 10 KB stays in flight
// under tile t's ~4000-cy compute.
__global__ void __launch_bounds__(64, 2) pgo_kernel(
        const float* __restrict__ Twc,
        const float* __restrict__ Tp_inv,
        const float* __restrict__ To_inv,
        const float* __restrict__ pw,
        const float* __restrict__ ow,
        const int*   __restrict__ edges,
        const float* __restrict__ T_lc,
        float*       __restrict__ out,
        int n_) {
    __shared__ float lds[2][BUF_FLOATS];
    const unsigned n = (unsigned)n_;
    const unsigned lane = threadIdx.x;
    const unsigned T = (n + 63u) >> 6;
    const unsigned stride = gridDim.x;
    unsigned tile = blockIdx.x;
    if (tile >= T) return;

    // ---- prologue ----
    stage_tile(lds[0], tile, Tp_inv, To_inv, T_lc, pw, ow, n, lane);
    unsigned it0 = tile*64u + lane;
    unsigned ix0 = it0 < n ? it0 : (n - 1u);
    v2i  e_cur  = *reinterpret_cast<const v2i*>(edges + 2u*ix0);
    Sim3 Ti_cur = load_sim3(Twc + ix0*8u);
    Sim3 Tj_cur = load_sim3(Twc + ix0*8u + 8u);
    asm volatile("s_waitcnt vmcnt(0)" ::: "memory");
    __builtin_amdgcn_sched_barrier(0);

    unsigned cur = 0;
    while (true) {
        unsigned nxt = tile + stride;
        bool hasnxt = nxt < T;

        // ---- issue long-latency ops first: stage(next), next direct
        // regs, gathers for current ----
        v2i e_n; Sim3 Ti_n, Tj_n;
        if (hasnxt) {
            stage_tile(lds[cur ^ 1u], nxt, Tp_inv, To_inv, T_lc, pw, ow, n, lane);
            unsigned it = nxt*64u + lane;
            unsigned ix = it < n ? it : (n - 1u);
            e_n  = *reinterpret_cast<const v2i*>(edges + 2u*ix);
            Ti_n = load_sim3(Twc + ix*8u);
            Tj_n = load_sim3(Twc + ix*8u + 8u);
        }
        Sim3 Ta = load_sim3(Twc + (unsigned)e_cur.x * 8u);
        Sim3 Tb = load_sim3(Twc + (unsigned)e_cur.y * 8u);
        __builtin_amdgcn_sched_barrier(0);   // pin load issue before compute

        // ---- operand fetch for current tile: LDS (staged, drained by
        // last iteration's vmcnt) -- or direct loads on the FINAL tile
        // (avoids every tail-clamp hazard; wave-uniform branch) ----
        unsigned item = tile*64u + lane;
        unsigned ixc  = item < n ? item : (n - 1u);
        Sim3 Tp_, To_, Tl_;
        float pwv[7], owv[7];
        if (tile == T - 1u) {
            Tp_ = load_sim3(Tp_inv + ixc*8u);
            To_ = load_sim3(To_inv + ixc*8u);
            Tl_ = load_sim3(T_lc  + ixc*8u);
            #pragma unroll
            for (int k = 0; k < 7; ++k) {
                pwv[k] = pw[ixc*7u + k];
                owv[k] = ow[ixc*7u + k];
            }
        } else {
            const float* B = lds[cur];
            Tp_ = lds_sim3_split(B + TPo + lane*4u);
            To_ = lds_sim3_split(B + TOo + lane*4u);
            Tl_ = lds_sim3_split(B + TLo + lane*4u);
            #pragma unroll
            for (int k = 0; k < 7; ++k) {
                pwv[k] = B[PWo + lane*7u + k];
                owv[k] = B[OWo + lane*7u + k];
            }
        }

        // ---- phases 1+2: prior/odom logs ----
        Sim3 delta = sim3_mul(sim3_inv(Ti_cur), Tj_cur);
        float acc[7], r[7];
        sim3_log(sim3_mul(delta, Tp_), r);
        #pragma unroll
        for (int k = 0; k < 7; ++k) acc[k] = r[k] * pwv[k];
        sim3_log(sim3_mul(delta, To_), r);
        #pragma unroll
        for (int k = 0; k < 7; ++k) acc[k] = fmaf(r[k], owv[k], acc[k]);

        // gathers (issued ~2800 cy ago) + stage(next) drain here
        asm volatile("s_waitcnt vmcnt(0)" ::: "memory");
        __builtin_amdgcn_sched_barrier(0);

        // ---- phase 3: loop-closure log ----
        sim3_log(sim3_mul(sim3_mul(sim3_inv(Ta), Tb), Tl_), r);
        if (item < n) {
            #pragma unroll
            for (int k = 0; k < 7; ++k)
                out[item*7u + k] = acc[k] + r[k];
        }

        if (!hasnxt) break;
        tile = nxt; cur ^= 1u;
        e_cur = e_n; Ti_cur = Ti_n; Tj_cur = Tj_n;
    }
}

extern "C" void kernel_launch(void* const* d_in, const int* in_sizes, int n_in,
                              void* d_out, int out_size, void* d_ws, size_t ws_size,
                              hipStream_t stream) {
    const float* Twc   = (const float*)d_in[0];
    const float* Tp    = (const float*)d_in[1];
    const float* To    = (const float*)d_in[2];
    const float* pw    = (const float*)d_in[3];
    const float* ow    = (const float*)d_in[4];
    const int*   edges = (const int*)d_in[5];
    const float* Tlc   = (const float*)d_in[6];
    float* out = (float*)d_out;

    int n = in_sizes[1] / 8;              // N_FRAME - 1
    int T = (n + 63) / 64;                // 64-item tiles
    int grid = T < 2048 ? T : 2048;       // persistent blocks
    pgo_kernel<<<grid, 64, 0, stream>>>(Twc, Tp, To, pw, ow, edges, Tlc, out, n);
}